// Round 15
// baseline (633.655 us; speedup 1.0000x reference)
//
#include <hip/hip_runtime.h>

// PNALayer: B=4, Nc=512, Nf=256, F_NHID=C_NHID=64, U_HID=U_OUT=128, M_INIT=1600, M_HID=256, M_OUT=64
// ALL I/O float32. R15 = R14 (first-ever pass, absmax 0.0156) + LDS zero-init everywhere
// (kills call-1 vs call-2+ divergence via stale LDS) + m1 kept f32 in LDS (only W2 bf16).

__device__ __forceinline__ unsigned short f2bf(float f) {
    union { float f; unsigned int u; } x; x.f = f;
    unsigned int u = x.u + 0x7FFFu + ((x.u >> 16) & 1u);
    return (unsigned short)(u >> 16);
}
__device__ __forceinline__ float blo(unsigned int u) {
    union { unsigned int u; float f; } x; x.u = u << 16; return x.f;
}
__device__ __forceinline__ float bhi(unsigned int u) {
    union { unsigned int u; float f; } x; x.u = u & 0xFFFF0000u; return x.f;
}

// Stub-parity symbol (harmless).
__global__ void PNALayer_35081292874189_kernel() {}

// ---------------- workspace layout (bytes), all f32 ----------------
#define OFF_AC     0u          // 2048*128 f32 = 1048576
#define OFF_AF     1048576u    // 1024*128 f32 = 524288
#define OFF_DEGC   1572864u    // 2048 f32
#define OFF_DEGF   1581056u    // 1024 f32
#define OFF_SCALE  1585152u    // 2048 f32
#define OFF_SINV   1593344u    // 2048 f32
#define OFF_FEATS  1601536u    // 2048*1600 f32 = 13107200
#define OFF_HMID   14708736u   // 2048*256 f32  = 2097152
#define WS_NEED    16805888u

__global__ void PNALayer_ws_fail(float* out, int n) {
    int i = blockIdx.x * 256 + threadIdx.x;
    if (i < n) out[i] = 2500.0f;
}

// K1: A_c = h_cus@W1[0:64]+b1, A_f = h_fac@W1[64:128], degrees (all f32)
__global__ void PNALayer_prep1(
    const float* h_fac, const float* h_cus, const float* adj,
    const float* U_W1, const float* U_b1,
    float* wsAc, float* wsAf, float* wsDegC, float* wsDegF)
{
    __shared__ float sH[64];
    __shared__ float sRed[256];
    int bid = blockIdx.x, t = threadIdx.x;
    if (t < 64) sH[t] = 0.f;
    sRed[t] = 0.f;
    __syncthreads();

    if (bid < 1024) {
        int b = bid >> 8, f = bid & 255;
        if (t < 64) sH[t] = h_fac[(b * 256 + f) * 64 + t];
        __syncthreads();
        if (t < 128) {
            float acc = 0.f;
            for (int k = 0; k < 64; ++k)
                acc += sH[k] * U_W1[(64 + k) * 128 + t];
            wsAf[(b * 256 + f) * 128 + t] = acc;
        }
        float v = adj[(b * 512 + t) * 256 + f] + adj[(b * 512 + t + 256) * 256 + f];
        sRed[t] = v; __syncthreads();
        for (int s = 128; s > 0; s >>= 1) { if (t < s) sRed[t] += sRed[t + s]; __syncthreads(); }
        if (t == 0) wsDegF[b * 256 + f] = sRed[0];
    } else {
        int bc = bid - 1024;
        if (t < 64) sH[t] = h_cus[bc * 64 + t];
        __syncthreads();
        if (t < 128) {
            float acc = U_b1[t];
            for (int k = 0; k < 64; ++k)
                acc += sH[k] * U_W1[k * 128 + t];
            wsAc[bc * 128 + t] = acc;
        }
        float v = adj[bc * 256 + t];
        sRed[t] = v; __syncthreads();
        for (int s = 128; s > 0; s >>= 1) { if (t < s) sRed[t] += sRed[t + s]; __syncthreads(); }
        if (t == 0) wsDegC[bc] = sRed[0];
    }
}

// K2: avg_d, scale, scale_inv per batch
__global__ void PNALayer_prep2(
    const float* wsDegC, const float* wsDegF, float* wsScale, float* wsSinv)
{
    __shared__ float sRed[256];
    __shared__ float sAvg;
    int b = blockIdx.x, t = threadIdx.x;
    sRed[t] = 0.f;
    if (t == 0) sAvg = 0.f;
    __syncthreads();
    float v = logf(wsDegC[b * 512 + t] + 1.f) + logf(wsDegC[b * 512 + t + 256] + 1.f)
            + logf(wsDegF[b * 256 + t] + 1.f);
    sRed[t] = v; __syncthreads();
    for (int s = 128; s > 0; s >>= 1) { if (t < s) sRed[t] += sRed[t + s]; __syncthreads(); }
    if (t == 0) sAvg = sRed[0] / 768.f;
    __syncthreads();
    float avg = sAvg;
    for (int c = t; c < 512; c += 256) {
        float lg = logf(wsDegC[b * 512 + c] + 1.f);
        float sc = lg / avg;
        float si = (sc != 0.f) ? 1.f / sc : 0.f;
        wsScale[b * 512 + c] = sc;
        wsSinv[b * 512 + c] = si;
    }
}

// K3: per-(b,c) edge MLP + masked aggregation -> feats row (1600, f32)
// LDS (63488 B): sW2 bf16[128*136] @0 | sM1f f32[32*132] @34816 | sRed f32[2048] @51712 |
//   sE @59904 | sMk @60928 | sAc @61952 | sWe @62464 | sB2 @62976 (each f32)
__global__ void PNALayer_edge(
    const float* h_cus, const float* edge, const float* adj,
    const float* U_W1, const float* U_b2, const float* U_W2,
    const float* wsAc, const float* wsAf, const float* wsDegC,
    const float* wsScale, const float* wsSinv,
    float* feats)
{
    __shared__ __align__(16) unsigned char smem[63488];
    unsigned short* sW2 = (unsigned short*)(smem);
    float* sM1f = (float*)(smem + 34816);
    float* sRed = (float*)(smem + 51712);
    float* sE   = (float*)(smem + 59904);
    float* sMk  = (float*)(smem + 60928);
    float* sAc  = (float*)(smem + 61952);
    float* sWe  = (float*)(smem + 62464);
    float* sB2  = (float*)(smem + 62976);

    int bc = blockIdx.x;
    int b  = bc >> 9;
    int t  = threadIdx.x;

    // Zero-init ALL LDS: stale-LDS reads are structurally impossible.
    {
        unsigned int* z = (unsigned int*)smem;
        for (int i = t; i < 15872; i += 256) z[i] = 0u;
    }
    __syncthreads();

    // Stage U_W2 (128x128 f32) -> bf16 LDS rows padded to 136
    for (int rep = 0; rep < 16; ++rep) {
        int vi = rep * 256 + t;            // 0..4095, each covers 4 elems
        int k = vi >> 5, jb = (vi & 31) * 4;
        float4 w = *(const float4*)(U_W2 + k * 128 + jb);
        sW2[k * 136 + jb + 0] = f2bf(w.x);
        sW2[k * 136 + jb + 1] = f2bf(w.y);
        sW2[k * 136 + jb + 2] = f2bf(w.z);
        sW2[k * 136 + jb + 3] = f2bf(w.w);
    }
    sE[t]  = edge[bc * 256 + t];
    sMk[t] = (adj[bc * 256 + t] > 0.f) ? 1.f : 0.f;
    if (t < 128) {
        sAc[t] = wsAc[bc * 128 + t];
        sWe[t] = U_W1[128 * 128 + t];
        sB2[t] = U_b2[t];
    }
    __syncthreads();

    int j0 = (t & 15) * 8;
    int f0 = (t >> 4) * 2;      // 16 groups x 2 rows = 32-row tile
    float b2v[8];
    for (int j = 0; j < 8; ++j) b2v[j] = sB2[j0 + j];

    float aS[8], aQ[8], aMx[8], aMn[8];
    for (int j = 0; j < 8; ++j) { aS[j] = 0.f; aQ[j] = 0.f; aMx[j] = -1e30f; aMn[j] = 1e30f; }

    for (int ft = 0; ft < 8; ++ft) {
        // stage m1 = relu(ac + af + e*we) -> f32, 32 rows x 128 k
        for (int i = 0; i < 16; ++i) {
            int idx = i * 256 + t;
            int fl = idx >> 7, k = idx & 127;
            int f = ft * 32 + fl;
            float m = sAc[k] + wsAf[(b * 256 + f) * 128 + k] + sE[f] * sWe[k];
            sM1f[fl * 132 + k] = fmaxf(m, 0.f);
        }
        __syncthreads();

        float acc[2][8];
        for (int ff = 0; ff < 2; ++ff)
            for (int j = 0; j < 8; ++j) acc[ff][j] = 0.f;

        for (int k = 0; k < 128; ++k) {
            uint4 wr = *(const uint4*)(sW2 + k * 136 + j0);
            float wv[8];
            wv[0] = blo(wr.x); wv[1] = bhi(wr.x); wv[2] = blo(wr.y); wv[3] = bhi(wr.y);
            wv[4] = blo(wr.z); wv[5] = bhi(wr.z); wv[6] = blo(wr.w); wv[7] = bhi(wr.w);
            float m0 = sM1f[(f0 + 0) * 132 + k];
            float m1 = sM1f[(f0 + 1) * 132 + k];
            for (int j = 0; j < 8; ++j) {
                acc[0][j] += m0 * wv[j];
                acc[1][j] += m1 * wv[j];
            }
        }

        for (int ff = 0; ff < 2; ++ff) {
            int f = ft * 32 + f0 + ff;
            if (sMk[f] > 0.f) {
                for (int j = 0; j < 8; ++j) {
                    float v = acc[ff][j] + b2v[j];
                    aS[j] += v; aQ[j] += v * v;
                    aMx[j] = fmaxf(aMx[j], v); aMn[j] = fminf(aMn[j], v);
                }
            }
        }
        __syncthreads();
    }

    int fg = t >> 4;
    float rS = 0.f, rQ = 0.f, rMx = 0.f, rMn = 0.f;

    for (int j = 0; j < 8; ++j) sRed[fg * 128 + j0 + j] = aS[j];
    __syncthreads();
    if (t < 128) { rS = sRed[t]; for (int g = 1; g < 16; ++g) rS += sRed[g * 128 + t]; }
    __syncthreads();
    for (int j = 0; j < 8; ++j) sRed[fg * 128 + j0 + j] = aQ[j];
    __syncthreads();
    if (t < 128) { rQ = sRed[t]; for (int g = 1; g < 16; ++g) rQ += sRed[g * 128 + t]; }
    __syncthreads();
    for (int j = 0; j < 8; ++j) sRed[fg * 128 + j0 + j] = aMx[j];
    __syncthreads();
    if (t < 128) { rMx = sRed[t]; for (int g = 1; g < 16; ++g) rMx = fmaxf(rMx, sRed[g * 128 + t]); }
    __syncthreads();
    for (int j = 0; j < 8; ++j) sRed[fg * 128 + j0 + j] = aMn[j];
    __syncthreads();
    if (t < 128) { rMn = sRed[t]; for (int g = 1; g < 16; ++g) rMn = fminf(rMn, sRed[g * 128 + t]); }

    if (t < 128) {
        float cnt = wsDegC[bc];
        float mean = rS / cnt;
        float var  = fmaxf(rQ / cnt - mean * mean, 0.f);
        float stdv = sqrtf(var);
        float sc = wsScale[bc], si = wsSinv[bc];
        float* fr = feats + bc * 1600;
        int j = t;
        fr[64 + j]   = mean; fr[192 + j]  = mean * sc; fr[320 + j]  = mean * si;
        fr[448 + j]  = stdv; fr[576 + j]  = stdv * sc; fr[704 + j]  = stdv * si;
        fr[832 + j]  = rMx;  fr[960 + j]  = rMx * sc;  fr[1088 + j] = rMx * si;
        fr[1216 + j] = rMn;  fr[1344 + j] = rMn * sc;  fr[1472 + j] = rMn * si;
    } else if (t < 192) {
        int j = t - 128;
        feats[bc * 1600 + j] = h_cus[bc * 64 + j];
    }
}

// K4: h_mid = relu(feats @ M_W1 + b1)  (f32 tiled GEMM 64x64)
__global__ void PNALayer_mlp1(
    const float* feats, const float* M_W1, const float* M_b1, float* h_mid)
{
    __shared__ __align__(16) float sA[64 * 68];
    __shared__ __align__(16) float sB[64 * 68];
    int t = threadIdx.x;
    {   // zero-init (incl. pads)
        for (int i = t; i < 64 * 68; i += 256) { sA[i] = 0.f; sB[i] = 0.f; }
    }
    __syncthreads();
    int rb = (blockIdx.x >> 2) * 64, cb = (blockIdx.x & 3) * 64;

    int j0 = (t & 7) * 8;
    int r0 = (t >> 3) * 2;
    float acc[2][8];
    for (int rr = 0; rr < 2; ++rr)
        for (int j = 0; j < 8; ++j) acc[rr][j] = 0.f;

    for (int kt = 0; kt < 25; ++kt) {
        int kb = kt * 64;
        for (int rep = 0; rep < 4; ++rep) {
            int vi = rep * 256 + t;          // 0..1023 float4s each
            int row = vi >> 4, c = (vi & 15) * 4;
            *(float4*)(sA + row * 68 + c) = *(const float4*)(feats + (rb + row) * 1600 + kb + c);
            *(float4*)(sB + row * 68 + c) = *(const float4*)(M_W1 + (kb + row) * 256 + cb + c);
        }
        __syncthreads();
        for (int k = 0; k < 64; ++k) {
            float a0 = sA[(r0 + 0) * 68 + k];
            float a1 = sA[(r0 + 1) * 68 + k];
            const float* wr = sB + k * 68 + j0;
            for (int j = 0; j < 8; ++j) {
                float w = wr[j];
                acc[0][j] += a0 * w;
                acc[1][j] += a1 * w;
            }
        }
        __syncthreads();
    }
    for (int rr = 0; rr < 2; ++rr) {
        for (int j = 0; j < 8; ++j) {
            int col = cb + j0 + j;
            float h = fmaxf(acc[rr][j] + M_b1[col], 0.f);
            h_mid[(rb + r0 + rr) * 256 + col] = h;
        }
    }
}

// K5: out = h_mid @ M_W2 + b2  (f32)
__global__ void PNALayer_mlp2(
    const float* h_mid, const float* M_W2, const float* M_b2, float* out)
{
    int idx = blockIdx.x * 256 + threadIdx.x;   // [0, 131072)
    int row = idx >> 6, j = idx & 63;
    float acc = M_b2[j];
    const float* hr = h_mid + row * 256;
    for (int k = 0; k < 256; ++k)
        acc += hr[k] * M_W2[k * 64 + j];
    out[idx] = acc;
}

extern "C" void kernel_launch(void* const* d_in, const int* in_sizes, int n_in,
                              void* d_out, int out_size, void* d_ws, size_t ws_size,
                              hipStream_t stream) {
    const float* h_fac = (const float*)d_in[0];
    const float* h_cus = (const float*)d_in[1];
    const float* edge  = (const float*)d_in[2];
    const float* adj   = (const float*)d_in[3];
    const float* U_W1  = (const float*)d_in[4];
    const float* U_b1  = (const float*)d_in[5];
    const float* U_W2  = (const float*)d_in[6];
    const float* U_b2  = (const float*)d_in[7];
    const float* M_W1  = (const float*)d_in[8];
    const float* M_b1  = (const float*)d_in[9];
    const float* M_W2  = (const float*)d_in[10];
    const float* M_b2  = (const float*)d_in[11];
    (void)in_sizes; (void)n_in;

    float* outp = (float*)d_out;
    int nblk_out = (out_size + 255) / 256;

    if (ws_size < (size_t)WS_NEED) {
        PNALayer_ws_fail<<<nblk_out, 256, 0, stream>>>(outp, out_size);
        return;
    }

    char* ws = (char*)d_ws;
    float* wsAc   = (float*)(ws + OFF_AC);
    float* wsAf   = (float*)(ws + OFF_AF);
    float* wsDegC = (float*)(ws + OFF_DEGC);
    float* wsDegF = (float*)(ws + OFF_DEGF);
    float* wsScal = (float*)(ws + OFF_SCALE);
    float* wsSinv = (float*)(ws + OFF_SINV);
    float* wsFeat = (float*)(ws + OFF_FEATS);
    float* wsHmid = (float*)(ws + OFF_HMID);

    PNALayer_prep1<<<3072, 256, 0, stream>>>(
        h_fac, h_cus, adj, U_W1, U_b1, wsAc, wsAf, wsDegC, wsDegF);
    PNALayer_prep2<<<4, 256, 0, stream>>>(wsDegC, wsDegF, wsScal, wsSinv);
    PNALayer_edge<<<2048, 256, 0, stream>>>(
        h_cus, edge, adj, U_W1, U_b2, U_W2,
        wsAc, wsAf, wsDegC, wsScal, wsSinv, wsFeat);
    PNALayer_mlp1<<<128, 256, 0, stream>>>(wsFeat, M_W1, M_b1, wsHmid);
    PNALayer_mlp2<<<512, 256, 0, stream>>>(wsHmid, M_W2, M_b2, outp);
}

// Round 16
// 329.864 us; speedup vs baseline: 1.9210x; 1.9210x over previous
//
#include <hip/hip_runtime.h>

// PNALayer: B=4, Nc=512, Nf=256, F_NHID=C_NHID=64, U_HID=U_OUT=128, M_INIT=1600, M_HID=256, M_OUT=64
// ALL I/O float32. R16 = R15 (passing, 633us) + MFMA edge GEMM (bf16 frags, f32 acc).

using bs8 = __attribute__((ext_vector_type(8))) short;   // 8 bf16 in 4 VGPRs (MFMA A/B frag)
using f4  = __attribute__((ext_vector_type(4))) float;   // MFMA C/D frag

__device__ __forceinline__ unsigned short f2bf(float f) {
    union { float f; unsigned int u; } x; x.f = f;
    unsigned int u = x.u + 0x7FFFu + ((x.u >> 16) & 1u);
    return (unsigned short)(u >> 16);
}

// Stub-parity symbol (harmless).
__global__ void PNALayer_35081292874189_kernel() {}

// ---------------- workspace layout (bytes), all f32 ----------------
#define OFF_AC     0u          // 2048*128 f32 = 1048576
#define OFF_AF     1048576u    // 1024*128 f32 = 524288
#define OFF_DEGC   1572864u    // 2048 f32
#define OFF_DEGF   1581056u    // 1024 f32
#define OFF_SCALE  1585152u    // 2048 f32
#define OFF_SINV   1593344u    // 2048 f32
#define OFF_FEATS  1601536u    // 2048*1600 f32 = 13107200
#define OFF_HMID   14708736u   // 2048*256 f32  = 2097152
#define OFF_W2T    16805888u   // 128*128 f32   = 65536 (U_W2 transposed, n-major)
#define WS_NEED    16871424u

__global__ void PNALayer_ws_fail(float* out, int n) {
    int i = blockIdx.x * 256 + threadIdx.x;
    if (i < n) out[i] = 2500.0f;
}

// K1: A_c, A_f, degrees, and U_W2 transpose (4 extra blocks)
__global__ void PNALayer_prep1(
    const float* h_fac, const float* h_cus, const float* adj,
    const float* U_W1, const float* U_b1, const float* U_W2,
    float* wsAc, float* wsAf, float* wsDegC, float* wsDegF, float* wsW2T)
{
    __shared__ float sH[64];
    __shared__ float sRed[256];
    __shared__ float sT[64][65];
    int bid = blockIdx.x, t = threadIdx.x;

    if (bid < 1024) {
        int b = bid >> 8, f = bid & 255;
        if (t < 64) sH[t] = h_fac[(b * 256 + f) * 64 + t];
        __syncthreads();
        if (t < 128) {
            float acc = 0.f;
            for (int k = 0; k < 64; ++k)
                acc += sH[k] * U_W1[(64 + k) * 128 + t];
            wsAf[(b * 256 + f) * 128 + t] = acc;
        }
        float v = adj[(b * 512 + t) * 256 + f] + adj[(b * 512 + t + 256) * 256 + f];
        sRed[t] = v; __syncthreads();
        for (int s = 128; s > 0; s >>= 1) { if (t < s) sRed[t] += sRed[t + s]; __syncthreads(); }
        if (t == 0) wsDegF[b * 256 + f] = sRed[0];
    } else if (bid < 3072) {
        int bc = bid - 1024;
        if (t < 64) sH[t] = h_cus[bc * 64 + t];
        __syncthreads();
        if (t < 128) {
            float acc = U_b1[t];
            for (int k = 0; k < 64; ++k)
                acc += sH[k] * U_W1[k * 128 + t];
            wsAc[bc * 128 + t] = acc;
        }
        float v = adj[bc * 256 + t];
        sRed[t] = v; __syncthreads();
        for (int s = 128; s > 0; s >>= 1) { if (t < s) sRed[t] += sRed[t + s]; __syncthreads(); }
        if (t == 0) wsDegC[bc] = sRed[0];
    } else {
        // transpose U_W2 [k][n] -> wsW2T [n][k], 64x64 tiles
        int l = bid - 3072;           // 0..3
        int k0 = (l >> 1) * 64, n0 = (l & 1) * 64;
        for (int rep = 0; rep < 16; ++rep) {
            int idx = rep * 256 + t; int r = idx >> 6, c = idx & 63;
            sT[r][c] = U_W2[(k0 + r) * 128 + n0 + c];
        }
        __syncthreads();
        for (int rep = 0; rep < 16; ++rep) {
            int idx = rep * 256 + t; int r = idx >> 6, c = idx & 63;
            wsW2T[(n0 + r) * 128 + k0 + c] = sT[c][r];
        }
    }
}

// K2: avg_d, scale, scale_inv per batch
__global__ void PNALayer_prep2(
    const float* wsDegC, const float* wsDegF, float* wsScale, float* wsSinv)
{
    __shared__ float sRed[256];
    __shared__ float sAvg;
    int b = blockIdx.x, t = threadIdx.x;
    float v = logf(wsDegC[b * 512 + t] + 1.f) + logf(wsDegC[b * 512 + t + 256] + 1.f)
            + logf(wsDegF[b * 256 + t] + 1.f);
    sRed[t] = v; __syncthreads();
    for (int s = 128; s > 0; s >>= 1) { if (t < s) sRed[t] += sRed[t + s]; __syncthreads(); }
    if (t == 0) sAvg = sRed[0] / 768.f;
    __syncthreads();
    float avg = sAvg;
    for (int c = t; c < 512; c += 256) {
        float lg = logf(wsDegC[b * 512 + c] + 1.f);
        float sc = lg / avg;
        float si = (sc != 0.f) ? 1.f / sc : 0.f;
        wsScale[b * 512 + c] = sc;
        wsSinv[b * 512 + c] = si;
    }
}

// K3: per-(b,c) edge MLP via MFMA + masked aggregation -> feats row (1600, f32)
// LDS (64000 B): sW2T bf16[128][136] @0 | sM1 bf16[64][136] @34816 | sRed f32[2048] @52224 |
//   sE @60416 | sMk @61440 | sAc @62464 | sWe @62976 | sB2 @63488 (each f32)
__global__ __launch_bounds__(256, 2) void PNALayer_edge(
    const float* h_cus, const float* edge, const float* adj,
    const float* U_W1, const float* U_b2,
    const float* wsAc, const float* wsAf, const float* wsW2T, const float* wsDegC,
    const float* wsScale, const float* wsSinv,
    float* feats)
{
    __shared__ __align__(16) unsigned char smem[64000];
    unsigned short* sW2T = (unsigned short*)(smem);
    unsigned short* sM1  = (unsigned short*)(smem + 34816);
    float* sRed = (float*)(smem + 52224);
    float* sE   = (float*)(smem + 60416);
    float* sMk  = (float*)(smem + 61440);
    float* sAc  = (float*)(smem + 62464);
    float* sWe  = (float*)(smem + 62976);
    float* sB2  = (float*)(smem + 63488);

    int bc = blockIdx.x;
    int b  = bc >> 9;
    int t  = threadIdx.x;
    int w = t >> 6, quad = (t >> 4) & 3, ln = t & 15;

    // Zero-init ALL LDS (stale-LDS reads structurally impossible; pads read as 0)
    {
        unsigned int* z = (unsigned int*)smem;
        for (int i = t; i < 16000; i += 256) z[i] = 0u;
    }
    __syncthreads();

    // Stage W2T (n-major f32) -> bf16 LDS rows padded to 136
    for (int rep = 0; rep < 16; ++rep) {
        int vi = rep * 256 + t;            // 0..4095 float4s
        int n = vi >> 5, kb = (vi & 31) * 4;
        float4 wv = *(const float4*)(wsW2T + n * 128 + kb);
        uint2 p;
        p.x = (unsigned int)f2bf(wv.x) | ((unsigned int)f2bf(wv.y) << 16);
        p.y = (unsigned int)f2bf(wv.z) | ((unsigned int)f2bf(wv.w) << 16);
        *(uint2*)(sW2T + n * 136 + kb) = p;
    }
    sE[t]  = edge[bc * 256 + t];
    sMk[t] = (adj[bc * 256 + t] > 0.f) ? 1.f : 0.f;
    if (t < 128) {
        sAc[t] = wsAc[bc * 128 + t];
        sWe[t] = U_W1[128 * 128 + t];
        sB2[t] = U_b2[t];
    }
    __syncthreads();

    float b2v[8];
    for (int nt = 0; nt < 8; ++nt) b2v[nt] = sB2[nt * 16 + ln];

    float aS[8], aQ[8], aMx[8], aMn[8];
    for (int j = 0; j < 8; ++j) { aS[j] = 0.f; aQ[j] = 0.f; aMx[j] = -1e30f; aMn[j] = 1e30f; }

    for (int ft = 0; ft < 4; ++ft) {
        // stage m1 = relu(ac + af + e*we) -> bf16, 64 rows x 128 k (coalesced float4 af loads)
        for (int i = 0; i < 8; ++i) {
            int idx = i * 256 + t;          // 0..2047
            int fl = idx >> 5, k = (idx & 31) * 4;
            int f = ft * 64 + fl;
            float4 af = *(const float4*)(wsAf + (b * 256 + f) * 128 + k);
            float e = sE[f];
            float m0 = fmaxf(sAc[k + 0] + af.x + e * sWe[k + 0], 0.f);
            float m1 = fmaxf(sAc[k + 1] + af.y + e * sWe[k + 1], 0.f);
            float m2 = fmaxf(sAc[k + 2] + af.z + e * sWe[k + 2], 0.f);
            float m3 = fmaxf(sAc[k + 3] + af.w + e * sWe[k + 3], 0.f);
            uint2 p;
            p.x = (unsigned int)f2bf(m0) | ((unsigned int)f2bf(m1) << 16);
            p.y = (unsigned int)f2bf(m2) | ((unsigned int)f2bf(m3) << 16);
            *(uint2*)(sM1 + fl * 136 + k) = p;
        }
        __syncthreads();

        // MFMA: wave w computes rows w*16..w*16+15 x all 128 cols
        f4 acc[8];
        for (int nt = 0; nt < 8; ++nt) acc[nt] = (f4){0.f, 0.f, 0.f, 0.f};
        int arow = w * 16 + ln;
        for (int kk = 0; kk < 4; ++kk) {
            int ko = kk * 32 + quad * 8;
            bs8 a = *(const bs8*)(sM1 + arow * 136 + ko);
            for (int nt = 0; nt < 8; ++nt) {
                bs8 bb = *(const bs8*)(sW2T + (nt * 16 + ln) * 136 + ko);
                acc[nt] = __builtin_amdgcn_mfma_f32_16x16x32_bf16(a, bb, acc[nt], 0, 0, 0);
            }
        }

        // masked aggregation (C/D: col=ln, row=quad*4+reg)
        for (int i = 0; i < 4; ++i) {
            int f = ft * 64 + w * 16 + quad * 4 + i;
            if (sMk[f] > 0.f) {
                for (int nt = 0; nt < 8; ++nt) {
                    float v = acc[nt][i] + b2v[nt];
                    aS[nt] += v; aQ[nt] += v * v;
                    aMx[nt] = fmaxf(aMx[nt], v); aMn[nt] = fminf(aMn[nt], v);
                }
            }
        }
        __syncthreads();   // all m1 reads done before restage
    }

    // cross-quad butterfly within wave (rows of this wave fully reduced)
    for (int nt = 0; nt < 8; ++nt) {
        aS[nt]  += __shfl_xor(aS[nt], 16, 64);  aS[nt]  += __shfl_xor(aS[nt], 32, 64);
        aQ[nt]  += __shfl_xor(aQ[nt], 16, 64);  aQ[nt]  += __shfl_xor(aQ[nt], 32, 64);
        aMx[nt] = fmaxf(aMx[nt], __shfl_xor(aMx[nt], 16, 64));
        aMx[nt] = fmaxf(aMx[nt], __shfl_xor(aMx[nt], 32, 64));
        aMn[nt] = fminf(aMn[nt], __shfl_xor(aMn[nt], 16, 64));
        aMn[nt] = fminf(aMn[nt], __shfl_xor(aMn[nt], 32, 64));
    }
    if (quad == 0) {
        for (int nt = 0; nt < 8; ++nt) {
            int col = nt * 16 + ln;
            sRed[(0 * 4 + w) * 128 + col] = aS[nt];
            sRed[(1 * 4 + w) * 128 + col] = aQ[nt];
            sRed[(2 * 4 + w) * 128 + col] = aMx[nt];
            sRed[(3 * 4 + w) * 128 + col] = aMn[nt];
        }
    }
    __syncthreads();

    if (t < 128) {
        int j = t;
        float rS = 0.f, rQ = 0.f, rMx = -1e30f, rMn = 1e30f;
        for (int ww = 0; ww < 4; ++ww) {
            rS += sRed[(0 * 4 + ww) * 128 + j];
            rQ += sRed[(1 * 4 + ww) * 128 + j];
            rMx = fmaxf(rMx, sRed[(2 * 4 + ww) * 128 + j]);
            rMn = fminf(rMn, sRed[(3 * 4 + ww) * 128 + j]);
        }
        float cnt = wsDegC[bc];
        float mean = rS / cnt;
        float var  = fmaxf(rQ / cnt - mean * mean, 0.f);
        float stdv = sqrtf(var);
        float sc = wsScale[bc], si = wsSinv[bc];
        float* fr = feats + bc * 1600;
        fr[64 + j]   = mean; fr[192 + j]  = mean * sc; fr[320 + j]  = mean * si;
        fr[448 + j]  = stdv; fr[576 + j]  = stdv * sc; fr[704 + j]  = stdv * si;
        fr[832 + j]  = rMx;  fr[960 + j]  = rMx * sc;  fr[1088 + j] = rMx * si;
        fr[1216 + j] = rMn;  fr[1344 + j] = rMn * sc;  fr[1472 + j] = rMn * si;
    } else if (t < 192) {
        int j = t - 128;
        feats[bc * 1600 + j] = h_cus[bc * 64 + j];
    }
}

// K4: h_mid = relu(feats @ M_W1 + b1)  (f32 tiled GEMM 64x64)
__global__ void PNALayer_mlp1(
    const float* feats, const float* M_W1, const float* M_b1, float* h_mid)
{
    __shared__ __align__(16) float sA[64 * 68];
    __shared__ __align__(16) float sB[64 * 68];
    int t = threadIdx.x;
    for (int i = t; i < 64 * 68; i += 256) { sA[i] = 0.f; sB[i] = 0.f; }
    __syncthreads();
    int rb = (blockIdx.x >> 2) * 64, cb = (blockIdx.x & 3) * 64;

    int j0 = (t & 7) * 8;
    int r0 = (t >> 3) * 2;
    float acc[2][8];
    for (int rr = 0; rr < 2; ++rr)
        for (int j = 0; j < 8; ++j) acc[rr][j] = 0.f;

    for (int kt = 0; kt < 25; ++kt) {
        int kb = kt * 64;
        for (int rep = 0; rep < 4; ++rep) {
            int vi = rep * 256 + t;
            int row = vi >> 4, c = (vi & 15) * 4;
            *(float4*)(sA + row * 68 + c) = *(const float4*)(feats + (rb + row) * 1600 + kb + c);
            *(float4*)(sB + row * 68 + c) = *(const float4*)(M_W1 + (kb + row) * 256 + cb + c);
        }
        __syncthreads();
        for (int k = 0; k < 64; ++k) {
            float a0 = sA[(r0 + 0) * 68 + k];
            float a1 = sA[(r0 + 1) * 68 + k];
            const float* wr = sB + k * 68 + j0;
            for (int j = 0; j < 8; ++j) {
                float w = wr[j];
                acc[0][j] += a0 * w;
                acc[1][j] += a1 * w;
            }
        }
        __syncthreads();
    }
    for (int rr = 0; rr < 2; ++rr) {
        for (int j = 0; j < 8; ++j) {
            int col = cb + j0 + j;
            float h = fmaxf(acc[rr][j] + M_b1[col], 0.f);
            h_mid[(rb + r0 + rr) * 256 + col] = h;
        }
    }
}

// K5: out = h_mid @ M_W2 + b2  (f32)
__global__ void PNALayer_mlp2(
    const float* h_mid, const float* M_W2, const float* M_b2, float* out)
{
    int idx = blockIdx.x * 256 + threadIdx.x;   // [0, 131072)
    int row = idx >> 6, j = idx & 63;
    float acc = M_b2[j];
    const float* hr = h_mid + row * 256;
    for (int k = 0; k < 256; ++k)
        acc += hr[k] * M_W2[k * 64 + j];
    out[idx] = acc;
}

extern "C" void kernel_launch(void* const* d_in, const int* in_sizes, int n_in,
                              void* d_out, int out_size, void* d_ws, size_t ws_size,
                              hipStream_t stream) {
    const float* h_fac = (const float*)d_in[0];
    const float* h_cus = (const float*)d_in[1];
    const float* edge  = (const float*)d_in[2];
    const float* adj   = (const float*)d_in[3];
    const float* U_W1  = (const float*)d_in[4];
    const float* U_b1  = (const float*)d_in[5];
    const float* U_W2  = (const float*)d_in[6];
    const float* U_b2  = (const float*)d_in[7];
    const float* M_W1  = (const float*)d_in[8];
    const float* M_b1  = (const float*)d_in[9];
    const float* M_W2  = (const float*)d_in[10];
    const float* M_b2  = (const float*)d_in[11];
    (void)in_sizes; (void)n_in;

    float* outp = (float*)d_out;
    int nblk_out = (out_size + 255) / 256;

    if (ws_size < (size_t)WS_NEED) {
        PNALayer_ws_fail<<<nblk_out, 256, 0, stream>>>(outp, out_size);
        return;
    }

    char* ws = (char*)d_ws;
    float* wsAc   = (float*)(ws + OFF_AC);
    float* wsAf   = (float*)(ws + OFF_AF);
    float* wsDegC = (float*)(ws + OFF_DEGC);
    float* wsDegF = (float*)(ws + OFF_DEGF);
    float* wsScal = (float*)(ws + OFF_SCALE);
    float* wsSinv = (float*)(ws + OFF_SINV);
    float* wsFeat = (float*)(ws + OFF_FEATS);
    float* wsHmid = (float*)(ws + OFF_HMID);
    float* wsW2T  = (float*)(ws + OFF_W2T);

    PNALayer_prep1<<<3076, 256, 0, stream>>>(
        h_fac, h_cus, adj, U_W1, U_b1, U_W2, wsAc, wsAf, wsDegC, wsDegF, wsW2T);
    PNALayer_prep2<<<4, 256, 0, stream>>>(wsDegC, wsDegF, wsScal, wsSinv);
    PNALayer_edge<<<2048, 256, 0, stream>>>(
        h_cus, edge, adj, U_W1, U_b2,
        wsAc, wsAf, wsW2T, wsDegC, wsScal, wsSinv, wsFeat);
    PNALayer_mlp1<<<128, 256, 0, stream>>>(wsFeat, M_W1, M_b1, wsHmid);
    PNALayer_mlp2<<<512, 256, 0, stream>>>(wsHmid, M_W2, M_b2, outp);
}

// Round 17
// 180.284 us; speedup vs baseline: 3.5148x; 1.8297x over previous
//
#include <hip/hip_runtime.h>

// PNALayer: B=4, Nc=512, Nf=256, F_NHID=C_NHID=64, U_HID=U_OUT=128, M_INIT=1600, M_HID=256, M_OUT=64
// ALL I/O float32. R17 = R16 (329us) + MFMA mlp1 (bf16 feats/W1T, 512-block grid).

using bs8 = __attribute__((ext_vector_type(8))) short;   // 8 bf16 in 4 VGPRs (MFMA A/B frag)
using f4  = __attribute__((ext_vector_type(4))) float;   // MFMA C/D frag

__device__ __forceinline__ unsigned short f2bf(float f) {
    union { float f; unsigned int u; } x; x.f = f;
    unsigned int u = x.u + 0x7FFFu + ((x.u >> 16) & 1u);
    return (unsigned short)(u >> 16);
}

// Stub-parity symbol (harmless).
__global__ void PNALayer_35081292874189_kernel() {}

// ---------------- workspace layout (bytes) ----------------
#define OFF_AC     0u          // 2048*128 f32 = 1048576
#define OFF_AF     1048576u    // 1024*128 f32 = 524288
#define OFF_DEGC   1572864u    // 2048 f32
#define OFF_DEGF   1581056u    // 1024 f32
#define OFF_SCALE  1585152u    // 2048 f32
#define OFF_SINV   1593344u    // 2048 f32
#define OFF_FEATB  1601536u    // 2048*1600 bf16 = 6553600 (+256 slack for K-pad overread)
#define OFF_HMID   8155392u    // 2048*256 f32   = 2097152
#define OFF_W2T    10252544u   // 128*128 f32    = 65536 (U_W2^T, n-major)
#define OFF_W1TB   10318080u   // 256*1664 bf16  = 851968 (M_W1^T, n-major, K zero-padded to 1664)
#define WS_NEED    11170048u

__global__ void PNALayer_ws_fail(float* out, int n) {
    int i = blockIdx.x * 256 + threadIdx.x;
    if (i < n) out[i] = 2500.0f;
}

// K1: A_c, A_f, degrees, U_W2 transpose (4 blocks), M_W1 transpose->bf16 (100 blocks), pad (1)
__global__ void PNALayer_prep1(
    const float* h_fac, const float* h_cus, const float* adj,
    const float* U_W1, const float* U_b1, const float* U_W2, const float* M_W1,
    float* wsAc, float* wsAf, float* wsDegC, float* wsDegF,
    float* wsW2T, unsigned short* wsW1Tb)
{
    __shared__ float sH[64];
    __shared__ float sRed[256];
    __shared__ float sT[64][65];
    int bid = blockIdx.x, t = threadIdx.x;

    if (bid < 1024) {
        int b = bid >> 8, f = bid & 255;
        if (t < 64) sH[t] = h_fac[(b * 256 + f) * 64 + t];
        __syncthreads();
        if (t < 128) {
            float acc = 0.f;
            for (int k = 0; k < 64; ++k)
                acc += sH[k] * U_W1[(64 + k) * 128 + t];
            wsAf[(b * 256 + f) * 128 + t] = acc;
        }
        float v = adj[(b * 512 + t) * 256 + f] + adj[(b * 512 + t + 256) * 256 + f];
        sRed[t] = v; __syncthreads();
        for (int s = 128; s > 0; s >>= 1) { if (t < s) sRed[t] += sRed[t + s]; __syncthreads(); }
        if (t == 0) wsDegF[b * 256 + f] = sRed[0];
    } else if (bid < 3072) {
        int bc = bid - 1024;
        if (t < 64) sH[t] = h_cus[bc * 64 + t];
        __syncthreads();
        if (t < 128) {
            float acc = U_b1[t];
            for (int k = 0; k < 64; ++k)
                acc += sH[k] * U_W1[k * 128 + t];
            wsAc[bc * 128 + t] = acc;
        }
        float v = adj[bc * 256 + t];
        sRed[t] = v; __syncthreads();
        for (int s = 128; s > 0; s >>= 1) { if (t < s) sRed[t] += sRed[t + s]; __syncthreads(); }
        if (t == 0) wsDegC[bc] = sRed[0];
    } else if (bid < 3076) {
        // transpose U_W2 [k][n] -> wsW2T [n][k] f32, 64x64 tiles
        int l = bid - 3072;
        int k0 = (l >> 1) * 64, n0 = (l & 1) * 64;
        for (int rep = 0; rep < 16; ++rep) {
            int idx = rep * 256 + t; int r = idx >> 6, c = idx & 63;
            sT[r][c] = U_W2[(k0 + r) * 128 + n0 + c];
        }
        __syncthreads();
        for (int rep = 0; rep < 16; ++rep) {
            int idx = rep * 256 + t; int r = idx >> 6, c = idx & 63;
            wsW2T[(n0 + r) * 128 + k0 + c] = sT[c][r];
        }
    } else if (bid < 3176) {
        // transpose M_W1 [k][n] (1600x256) -> wsW1Tb [n][k] bf16, 64x64 tiles
        int l = bid - 3076;            // 0..99
        int k0 = (l % 25) * 64, n0 = (l / 25) * 64;
        for (int rep = 0; rep < 16; ++rep) {
            int idx = rep * 256 + t; int r = idx >> 6, c = idx & 63;
            sT[r][c] = M_W1[(k0 + r) * 256 + n0 + c];
        }
        __syncthreads();
        for (int rep = 0; rep < 16; ++rep) {
            int idx = rep * 256 + t; int r = idx >> 6, c = idx & 63;
            wsW1Tb[(n0 + r) * 1664 + k0 + c] = f2bf(sT[c][r]);
        }
    } else {
        // zero the K-pad region k in [1600,1664) for all 256 n
        for (int i = 0; i < 64; ++i) {
            int idx = i * 256 + t;     // 0..16383
            int n = idx >> 6, k = 1600 + (idx & 63);
            wsW1Tb[n * 1664 + k] = 0;
        }
    }
}

// K2: avg_d, scale, scale_inv per batch
__global__ void PNALayer_prep2(
    const float* wsDegC, const float* wsDegF, float* wsScale, float* wsSinv)
{
    __shared__ float sRed[256];
    __shared__ float sAvg;
    int b = blockIdx.x, t = threadIdx.x;
    float v = logf(wsDegC[b * 512 + t] + 1.f) + logf(wsDegC[b * 512 + t + 256] + 1.f)
            + logf(wsDegF[b * 256 + t] + 1.f);
    sRed[t] = v; __syncthreads();
    for (int s = 128; s > 0; s >>= 1) { if (t < s) sRed[t] += sRed[t + s]; __syncthreads(); }
    if (t == 0) sAvg = sRed[0] / 768.f;
    __syncthreads();
    float avg = sAvg;
    for (int c = t; c < 512; c += 256) {
        float lg = logf(wsDegC[b * 512 + c] + 1.f);
        float sc = lg / avg;
        float si = (sc != 0.f) ? 1.f / sc : 0.f;
        wsScale[b * 512 + c] = sc;
        wsSinv[b * 512 + c] = si;
    }
}

// K3: per-(b,c) edge MLP via MFMA + masked aggregation -> featB row (1600, bf16)
__global__ __launch_bounds__(256, 2) void PNALayer_edge(
    const float* h_cus, const float* edge, const float* adj,
    const float* U_W1, const float* U_b2,
    const float* wsAc, const float* wsAf, const float* wsW2T, const float* wsDegC,
    const float* wsScale, const float* wsSinv,
    unsigned short* featB)
{
    __shared__ __align__(16) unsigned char smem[64000];
    unsigned short* sW2T = (unsigned short*)(smem);
    unsigned short* sM1  = (unsigned short*)(smem + 34816);
    float* sRed = (float*)(smem + 52224);
    float* sE   = (float*)(smem + 60416);
    float* sMk  = (float*)(smem + 61440);
    float* sAc  = (float*)(smem + 62464);
    float* sWe  = (float*)(smem + 62976);
    float* sB2  = (float*)(smem + 63488);

    int bc = blockIdx.x;
    int b  = bc >> 9;
    int t  = threadIdx.x;
    int w = t >> 6, quad = (t >> 4) & 3, ln = t & 15;

    {
        unsigned int* z = (unsigned int*)smem;
        for (int i = t; i < 16000; i += 256) z[i] = 0u;
    }
    __syncthreads();

    for (int rep = 0; rep < 16; ++rep) {
        int vi = rep * 256 + t;
        int n = vi >> 5, kb = (vi & 31) * 4;
        float4 wv = *(const float4*)(wsW2T + n * 128 + kb);
        uint2 p;
        p.x = (unsigned int)f2bf(wv.x) | ((unsigned int)f2bf(wv.y) << 16);
        p.y = (unsigned int)f2bf(wv.z) | ((unsigned int)f2bf(wv.w) << 16);
        *(uint2*)(sW2T + n * 136 + kb) = p;
    }
    sE[t]  = edge[bc * 256 + t];
    sMk[t] = (adj[bc * 256 + t] > 0.f) ? 1.f : 0.f;
    if (t < 128) {
        sAc[t] = wsAc[bc * 128 + t];
        sWe[t] = U_W1[128 * 128 + t];
        sB2[t] = U_b2[t];
    }
    __syncthreads();

    float b2v[8];
    for (int nt = 0; nt < 8; ++nt) b2v[nt] = sB2[nt * 16 + ln];

    float aS[8], aQ[8], aMx[8], aMn[8];
    for (int j = 0; j < 8; ++j) { aS[j] = 0.f; aQ[j] = 0.f; aMx[j] = -1e30f; aMn[j] = 1e30f; }

    for (int ft = 0; ft < 4; ++ft) {
        for (int i = 0; i < 8; ++i) {
            int idx = i * 256 + t;
            int fl = idx >> 5, k = (idx & 31) * 4;
            int f = ft * 64 + fl;
            float4 af = *(const float4*)(wsAf + (b * 256 + f) * 128 + k);
            float e = sE[f];
            float m0 = fmaxf(sAc[k + 0] + af.x + e * sWe[k + 0], 0.f);
            float m1 = fmaxf(sAc[k + 1] + af.y + e * sWe[k + 1], 0.f);
            float m2 = fmaxf(sAc[k + 2] + af.z + e * sWe[k + 2], 0.f);
            float m3 = fmaxf(sAc[k + 3] + af.w + e * sWe[k + 3], 0.f);
            uint2 p;
            p.x = (unsigned int)f2bf(m0) | ((unsigned int)f2bf(m1) << 16);
            p.y = (unsigned int)f2bf(m2) | ((unsigned int)f2bf(m3) << 16);
            *(uint2*)(sM1 + fl * 136 + k) = p;
        }
        __syncthreads();

        f4 acc[8];
        for (int nt = 0; nt < 8; ++nt) acc[nt] = (f4){0.f, 0.f, 0.f, 0.f};
        int arow = w * 16 + ln;
        for (int kk = 0; kk < 4; ++kk) {
            int ko = kk * 32 + quad * 8;
            bs8 a = *(const bs8*)(sM1 + arow * 136 + ko);
            for (int nt = 0; nt < 8; ++nt) {
                bs8 bb = *(const bs8*)(sW2T + (nt * 16 + ln) * 136 + ko);
                acc[nt] = __builtin_amdgcn_mfma_f32_16x16x32_bf16(a, bb, acc[nt], 0, 0, 0);
            }
        }

        for (int i = 0; i < 4; ++i) {
            int f = ft * 64 + w * 16 + quad * 4 + i;
            if (sMk[f] > 0.f) {
                for (int nt = 0; nt < 8; ++nt) {
                    float v = acc[nt][i] + b2v[nt];
                    aS[nt] += v; aQ[nt] += v * v;
                    aMx[nt] = fmaxf(aMx[nt], v); aMn[nt] = fminf(aMn[nt], v);
                }
            }
        }
        __syncthreads();
    }

    for (int nt = 0; nt < 8; ++nt) {
        aS[nt]  += __shfl_xor(aS[nt], 16, 64);  aS[nt]  += __shfl_xor(aS[nt], 32, 64);
        aQ[nt]  += __shfl_xor(aQ[nt], 16, 64);  aQ[nt]  += __shfl_xor(aQ[nt], 32, 64);
        aMx[nt] = fmaxf(aMx[nt], __shfl_xor(aMx[nt], 16, 64));
        aMx[nt] = fmaxf(aMx[nt], __shfl_xor(aMx[nt], 32, 64));
        aMn[nt] = fminf(aMn[nt], __shfl_xor(aMn[nt], 16, 64));
        aMn[nt] = fminf(aMn[nt], __shfl_xor(aMn[nt], 32, 64));
    }
    if (quad == 0) {
        for (int nt = 0; nt < 8; ++nt) {
            int col = nt * 16 + ln;
            sRed[(0 * 4 + w) * 128 + col] = aS[nt];
            sRed[(1 * 4 + w) * 128 + col] = aQ[nt];
            sRed[(2 * 4 + w) * 128 + col] = aMx[nt];
            sRed[(3 * 4 + w) * 128 + col] = aMn[nt];
        }
    }
    __syncthreads();

    if (t < 128) {
        int j = t;
        float rS = 0.f, rQ = 0.f, rMx = -1e30f, rMn = 1e30f;
        for (int ww = 0; ww < 4; ++ww) {
            rS += sRed[(0 * 4 + ww) * 128 + j];
            rQ += sRed[(1 * 4 + ww) * 128 + j];
            rMx = fmaxf(rMx, sRed[(2 * 4 + ww) * 128 + j]);
            rMn = fminf(rMn, sRed[(3 * 4 + ww) * 128 + j]);
        }
        float cnt = wsDegC[bc];
        float mean = rS / cnt;
        float var  = fmaxf(rQ / cnt - mean * mean, 0.f);
        float stdv = sqrtf(var);
        float sc = wsScale[bc], si = wsSinv[bc];
        unsigned short* fr = featB + bc * 1600;
        fr[64 + j]   = f2bf(mean); fr[192 + j]  = f2bf(mean * sc); fr[320 + j]  = f2bf(mean * si);
        fr[448 + j]  = f2bf(stdv); fr[576 + j]  = f2bf(stdv * sc); fr[704 + j]  = f2bf(stdv * si);
        fr[832 + j]  = f2bf(rMx);  fr[960 + j]  = f2bf(rMx * sc);  fr[1088 + j] = f2bf(rMx * si);
        fr[1216 + j] = f2bf(rMn);  fr[1344 + j] = f2bf(rMn * sc);  fr[1472 + j] = f2bf(rMn * si);
    } else if (t < 192) {
        int j = t - 128;
        featB[bc * 1600 + j] = f2bf(h_cus[bc * 64 + j]);
    }
}

// K4: h_mid = relu(featB @ W1Tb^T + b1) via MFMA. Block = 16 rows x 64 cols, grid 512.
// LDS: sA bf16[16][136]=4352B, sB bf16[64][136]=17408B  (21760 B total)
__global__ __launch_bounds__(256) void PNALayer_mlp1(
    const unsigned short* featB, const unsigned short* wsW1Tb, const float* M_b1,
    float* h_mid)
{
    __shared__ __align__(16) unsigned short sA[16 * 136];
    __shared__ __align__(16) unsigned short sB[64 * 136];
    int t = threadIdx.x;
    int rb = (blockIdx.x >> 2) * 16, cb = (blockIdx.x & 3) * 64;
    int w = t >> 6, quad = (t >> 4) & 3, ln = t & 15;

    f4 acc = (f4){0.f, 0.f, 0.f, 0.f};

    for (int kt = 0; kt < 13; ++kt) {
        int kb = kt * 128;
        {   // stage A: 16 rows x 128 k (256 uint4, 1/thread)
            int row = t >> 4, c8 = (t & 15) * 8;
            *(uint4*)(sA + row * 136 + c8) =
                *(const uint4*)(featB + (rb + row) * 1600 + kb + c8);
        }
        for (int i = 0; i < 4; ++i) {   // stage B: 64 n-rows x 128 k (1024 uint4)
            int vi = i * 256 + t;
            int row = vi >> 4, c8 = (vi & 15) * 8;
            *(uint4*)(sB + row * 136 + c8) =
                *(const uint4*)(wsW1Tb + (cb + row) * 1664 + kb + c8);
        }
        __syncthreads();
        for (int kk = 0; kk < 4; ++kk) {
            int ko = kk * 32 + quad * 8;
            bs8 a = *(const bs8*)(sA + ln * 136 + ko);
            bs8 bb = *(const bs8*)(sB + (w * 16 + ln) * 136 + ko);
            acc = __builtin_amdgcn_mfma_f32_16x16x32_bf16(a, bb, acc, 0, 0, 0);
        }
        __syncthreads();
    }
    // C/D: col=ln (n), row=quad*4+i (m)
    int col = cb + w * 16 + ln;
    float b1v = M_b1[col];
    for (int i = 0; i < 4; ++i) {
        int row = rb + quad * 4 + i;
        h_mid[row * 256 + col] = fmaxf(acc[i] + b1v, 0.f);
    }
}

// K5: out = h_mid @ M_W2 + b2  (f32)
__global__ void PNALayer_mlp2(
    const float* h_mid, const float* M_W2, const float* M_b2, float* out)
{
    int idx = blockIdx.x * 256 + threadIdx.x;   // [0, 131072)
    int row = idx >> 6, j = idx & 63;
    float acc = M_b2[j];
    const float* hr = h_mid + row * 256;
    for (int k = 0; k < 256; ++k)
        acc += hr[k] * M_W2[k * 64 + j];
    out[idx] = acc;
}

extern "C" void kernel_launch(void* const* d_in, const int* in_sizes, int n_in,
                              void* d_out, int out_size, void* d_ws, size_t ws_size,
                              hipStream_t stream) {
    const float* h_fac = (const float*)d_in[0];
    const float* h_cus = (const float*)d_in[1];
    const float* edge  = (const float*)d_in[2];
    const float* adj   = (const float*)d_in[3];
    const float* U_W1  = (const float*)d_in[4];
    const float* U_b1  = (const float*)d_in[5];
    const float* U_W2  = (const float*)d_in[6];
    const float* U_b2  = (const float*)d_in[7];
    const float* M_W1  = (const float*)d_in[8];
    const float* M_b1  = (const float*)d_in[9];
    const float* M_W2  = (const float*)d_in[10];
    const float* M_b2  = (const float*)d_in[11];
    (void)in_sizes; (void)n_in;

    float* outp = (float*)d_out;
    int nblk_out = (out_size + 255) / 256;

    if (ws_size < (size_t)WS_NEED) {
        PNALayer_ws_fail<<<nblk_out, 256, 0, stream>>>(outp, out_size);
        return;
    }

    char* ws = (char*)d_ws;
    float*          wsAc   = (float*)(ws + OFF_AC);
    float*          wsAf   = (float*)(ws + OFF_AF);
    float*          wsDegC = (float*)(ws + OFF_DEGC);
    float*          wsDegF = (float*)(ws + OFF_DEGF);
    float*          wsScal = (float*)(ws + OFF_SCALE);
    float*          wsSinv = (float*)(ws + OFF_SINV);
    unsigned short* wsFeatB= (unsigned short*)(ws + OFF_FEATB);
    float*          wsHmid = (float*)(ws + OFF_HMID);
    float*          wsW2T  = (float*)(ws + OFF_W2T);
    unsigned short* wsW1Tb = (unsigned short*)(ws + OFF_W1TB);

    PNALayer_prep1<<<3177, 256, 0, stream>>>(
        h_fac, h_cus, adj, U_W1, U_b1, U_W2, M_W1,
        wsAc, wsAf, wsDegC, wsDegF, wsW2T, wsW1Tb);
    PNALayer_prep2<<<4, 256, 0, stream>>>(wsDegC, wsDegF, wsScal, wsSinv);
    PNALayer_edge<<<2048, 256, 0, stream>>>(
        h_cus, edge, adj, U_W1, U_b2,
        wsAc, wsAf, wsW2T, wsDegC, wsScal, wsSinv, wsFeatB);
    PNALayer_mlp1<<<512, 256, 0, stream>>>(wsFeatB, wsW1Tb, M_b1, wsHmid);
    PNALayer_mlp2<<<512, 256, 0, stream>>>(wsHmid, M_W2, M_b2, outp);
}